// Round 7
// baseline (117.242 us; speedup 1.0000x reference)
//
#include <hip/hip_runtime.h>
#include <hip/hip_bf16.h>
#include <cstdint>
#include <cstddef>

typedef unsigned short u16;
typedef __attribute__((ext_vector_type(8))) short bf16x8;
typedef __attribute__((ext_vector_type(4))) float f32x4;

constexpr int Bn = 4;
constexpr int Nq = 8192;
constexpr int Mk = 2048;
constexpr int C1c = 128;
constexpr int C2c = 256;
constexpr int H1c = 256;
constexpr int H2c = 128;

__device__ __forceinline__ float bf2f(u16 u) {
    union { uint32_t i; float f; } v;
    v.i = (uint32_t)u << 16;
    return v.f;
}
__device__ __forceinline__ u16 f2bf(float f) {
    const uint32_t x = __float_as_uint(f);
    return (u16)((x + 0x7FFFu + ((x >> 16) & 1u)) >> 16);
}

// ================= 3-NN: exact f32 compare, 8 lanes/query =================
__global__ __launch_bounds__(256, 5) void knn_kernel(
    const float* __restrict__ unknown, const float* __restrict__ known,
    int* __restrict__ idx_out, float* __restrict__ w_out)
{
    __shared__ float4 kp[Mk];  // (x, y, z, |k|^2), 32 KB
    const int bid = blockIdx.x;
    const int t = threadIdx.x;
    const int b = bid >> 8;
    const int n0 = (bid & 255) * 32;

    const float* kb = known + (size_t)b * Mk * 3;
    for (int i = t; i < Mk; i += 256) {
        const float x = kb[i * 3 + 0], y = kb[i * 3 + 1], z = kb[i * 3 + 2];
        kp[i] = make_float4(x, y, z, fmaf(x, x, fmaf(y, y, z * z)));
    }
    __syncthreads();

    const int q = n0 + (t >> 3);
    const int s = t & 7;
    const float* u = unknown + ((size_t)b * Nq + q) * 3;
    const float ux = u[0], uy = u[1], uz = u[2];
    const float nux = -2.0f * ux, nuy = -2.0f * uy, nuz = -2.0f * uz;
    const float uu = fmaf(ux, ux, fmaf(uy, uy, uz * uz));

    // track d' = |k|^2 - 2 u.k  (ordering identical to true squared distance)
    float d0 = 1e30f, d1 = 1e30f, d2 = 1e30f;
    int i0 = 0, i1 = 0, i2 = 0;

    auto ins = [&](float d, int i) {
        const bool c0 = d < d0, c1 = d < d1, c2 = d < d2;
        const float nd0 = fminf(d0, d);
        const float nd1 = __builtin_amdgcn_fmed3f(d0, d, d1);
        const float nd2 = __builtin_amdgcn_fmed3f(d1, d, d2);
        i2 = c1 ? i1 : (c2 ? i : i2);
        i1 = c0 ? i0 : (c1 ? i : i1);
        i0 = c0 ? i : i0;
        d0 = nd0; d1 = nd1; d2 = nd2;
    };

    #pragma unroll 8
    for (int it = 0; it < Mk / 8; ++it) {
        const int m = it * 8 + s;  // 8 consecutive float4 slots: conflict-free
        const float4 p = kp[m];
        const float d = fmaf(nux, p.x, fmaf(nuy, p.y, fmaf(nuz, p.z, p.w)));
        ins(d, m);
    }
    #pragma unroll
    for (int off = 1; off <= 4; off <<= 1) {
        const float e0 = __shfl_xor(d0, off), e1 = __shfl_xor(d1, off), e2 = __shfl_xor(d2, off);
        const int j0 = __shfl_xor(i0, off), j1 = __shfl_xor(i1, off), j2 = __shfl_xor(i2, off);
        ins(e0, j0);
        ins(e1, j1);
        ins(e2, j2);
    }
    if (s == 0) {
        const float f0 = d0 + uu, f1 = d1 + uu, f2 = d2 + uu;
        const float r0 = 1.0f / (f0 + 1e-8f);
        const float r1 = 1.0f / (f1 + 1e-8f);
        const float r2 = 1.0f / (f2 + 1e-8f);
        const float inv = 1.0f / (r0 + r1 + r2);
        const size_t base = ((size_t)b * Nq + q) * 3;
        idx_out[base + 0] = i0;
        idx_out[base + 1] = i1;
        idx_out[base + 2] = i2;
        w_out[base + 0] = r0 * inv;
        w_out[base + 1] = r1 * inv;
        w_out[base + 2] = r2 * inv;
    }
}

// ================= prep: cvt W1/W2 + transpose KF/UF =================
// block ranges: [0,96) cvt W1 | [96,128) cvt W2 | [128,640) KF | [640,1664) UF
__global__ __launch_bounds__(256) void prep_kernel(
    const float* __restrict__ W1, const float* __restrict__ W2,
    u16* __restrict__ W1b, u16* __restrict__ W2b,
    const float* __restrict__ KF, u16* __restrict__ KFt,
    const float* __restrict__ UF, u16* __restrict__ UFt)
{
    __shared__ float T[64][65];
    const int bid = blockIdx.x;
    const int t = threadIdx.x;

    if (bid < 128) {
        const float* X = (bid < 96) ? W1 : W2;
        u16* Y = (bid < 96) ? W1b : W2b;
        const int i = ((bid < 96) ? bid : (bid - 96)) * 256 + t;
        const float4 v = *(const float4*)&X[(size_t)i * 4];
        ushort4 o;
        o.x = f2bf(v.x); o.y = f2bf(v.y); o.z = f2bf(v.z); o.w = f2bf(v.w);
        *(ushort4*)&Y[(size_t)i * 4] = o;
        return;
    }
    const float* X;
    u16* Y;
    int C, M, m0, c0;
    if (bid < 640) {
        const int f = bid - 128;
        const int b = f >> 7, rem = f & 127;
        C = C2c; M = Mk; m0 = (rem >> 2) * 64; c0 = (rem & 3) * 64;
        X = KF + (size_t)b * C * M;
        Y = KFt + (size_t)b * M * C;
    } else {
        const int f = bid - 640;
        const int b = f >> 8, rem = f & 255;
        C = C1c; M = Nq; m0 = (rem >> 1) * 64; c0 = (rem & 1) * 64;
        X = UF + (size_t)b * C * M;
        Y = UFt + (size_t)b * M * C;
    }
    const int m4 = (t & 15) * 4, cr = t >> 4;
    #pragma unroll
    for (int i = 0; i < 4; ++i) {
        const float4 v = *(const float4*)&X[(size_t)(c0 + cr + i * 16) * M + m0 + m4];
        T[cr + i * 16][m4 + 0] = v.x;
        T[cr + i * 16][m4 + 1] = v.y;
        T[cr + i * 16][m4 + 2] = v.z;
        T[cr + i * 16][m4 + 3] = v.w;
    }
    __syncthreads();
    const int c4 = (t & 15) * 4, mr = t >> 4;
    #pragma unroll
    for (int i = 0; i < 4; ++i) {
        const int m = mr + i * 16;
        ushort4 o;
        o.x = f2bf(T[c4 + 0][m]);
        o.y = f2bf(T[c4 + 1][m]);
        o.z = f2bf(T[c4 + 2][m]);
        o.w = f2bf(T[c4 + 3][m]);
        *(ushort4*)&Y[(size_t)(m0 + m) * C + c0 + c4] = o;
    }
}

// ---------------- BN transform for staged B-operand (8 bf16) ----------------
__device__ __forceinline__ uint4 bnx(uint4 x, const float* scs, const float* bis, int k) {
    const u16* p = (const u16*)&x;
    u16 o[8];
    #pragma unroll
    for (int j = 0; j < 8; ++j)
        o[j] = f2bf(fmaxf(0.0f, fmaf(bf2f(p[j]), scs[k + j], bis[k + j])));
    return *(const uint4*)o;
}

// ================= bf16 MFMA bt-GEMM: C(M,N) = A(M,K) * Bt(N,K)^T =================
template <int GATHER, int OUT_BF16, int STATS, int BNIN>
__global__ __launch_bounds__(256) void mfma_gemm(
    const u16* __restrict__ A, int lda, size_t sA,
    const u16* __restrict__ Bt, int ldb, size_t sB,
    void* __restrict__ Cout, int ldc, size_t sC,
    int nK,
    const u16* __restrict__ Ptb,
    const int* __restrict__ idx, const float* __restrict__ wgt, int nrows,
    const float* __restrict__ bn_s, const float* __restrict__ bn_b,
    float* __restrict__ partS, float* __restrict__ partQ)
{
    __shared__ u16 As[4096];
    __shared__ u16 Bs[4096];
    __shared__ float scs[256], bis[256];
    __shared__ float sS[2][128], sQ[2][128];

    const int b = blockIdx.z;
    const int m0 = blockIdx.x * 128, n0 = blockIdx.y * 128;
    const int t = threadIdx.x;
    const int l = t & 63, wv = t >> 6;
    const int wr = wv >> 1, wc = wv & 1;

    if (BNIN) {
        scs[t] = bn_s[t];
        bis[t] = bn_b[t];
    }

    const u16* Ab = A + (size_t)b * sA;
    const u16* Btb = Bt + (size_t)b * sB;
    const int rA0 = t >> 2, rA1 = (t + 256) >> 2;
    const int ko = (t & 3) * 8;

    f32x4 acc[4][4];
    const f32x4 z = {0.0f, 0.0f, 0.0f, 0.0f};
    #pragma unroll
    for (int i = 0; i < 4; ++i)
        #pragma unroll
        for (int j = 0; j < 4; ++j) acc[i][j] = z;

    uint4 a0 = *(const uint4*)&Ab[(size_t)(m0 + rA0) * lda + ko];
    uint4 a1 = *(const uint4*)&Ab[(size_t)(m0 + rA1) * lda + ko];
    uint4 b0 = *(const uint4*)&Btb[(size_t)(n0 + rA0) * ldb + ko];
    uint4 b1 = *(const uint4*)&Btb[(size_t)(n0 + rA1) * ldb + ko];
    if (BNIN) __syncthreads();

    for (int kt = 0; kt < nK; ++kt) {
        *(uint4*)&As[t * 8] = a0;
        *(uint4*)&As[(t + 256) * 8] = a1;
        if (BNIN) {
            const int k = kt * 32 + ko;
            *(uint4*)&Bs[t * 8] = bnx(b0, scs, bis, k);
            *(uint4*)&Bs[(t + 256) * 8] = bnx(b1, scs, bis, k);
        } else {
            *(uint4*)&Bs[t * 8] = b0;
            *(uint4*)&Bs[(t + 256) * 8] = b1;
        }
        __syncthreads();
        if (kt + 1 < nK) {
            const int k0 = (kt + 1) * 32;
            a0 = *(const uint4*)&Ab[(size_t)(m0 + rA0) * lda + k0 + ko];
            a1 = *(const uint4*)&Ab[(size_t)(m0 + rA1) * lda + k0 + ko];
            b0 = *(const uint4*)&Btb[(size_t)(n0 + rA0) * ldb + k0 + ko];
            b1 = *(const uint4*)&Btb[(size_t)(n0 + rA1) * ldb + k0 + ko];
        }
        bf16x8 af[4], bf[4];
        #pragma unroll
        for (int f = 0; f < 4; ++f) {
            af[f] = *(const bf16x8*)&As[(wr * 64 + f * 16 + (l & 15)) * 32 + (l >> 4) * 8];
            bf[f] = *(const bf16x8*)&Bs[(wc * 64 + f * 16 + (l & 15)) * 32 + (l >> 4) * 8];
        }
        #pragma unroll
        for (int i = 0; i < 4; ++i)
            #pragma unroll
            for (int j = 0; j < 4; ++j)
                acc[i][j] = __builtin_amdgcn_mfma_f32_16x16x32_bf16(af[i], bf[j], acc[i][j], 0, 0, 0);
        __syncthreads();
    }

    const int cb = l & 15;
    const int rg = (l >> 4) * 4;
    float sj[4] = {0, 0, 0, 0}, qj[4] = {0, 0, 0, 0};
    #pragma unroll
    for (int i = 0; i < 4; ++i) {
        #pragma unroll
        for (int r = 0; r < 4; ++r) {
            const int R = m0 + wr * 64 + i * 16 + rg + r;
            const u16 *P0 = nullptr, *P1 = nullptr, *P2 = nullptr;
            float w0 = 0.0f, w1 = 0.0f, w2 = 0.0f;
            if (GATHER) {
                const size_t ib = ((size_t)b * nrows + R) * 3;
                const int j0 = idx[ib], j1 = idx[ib + 1], j2 = idx[ib + 2];
                w0 = wgt[ib];
                w1 = wgt[ib + 1];
                w2 = wgt[ib + 2];
                const u16* Pb = Ptb + (size_t)b * Mk * 256;
                P0 = Pb + (size_t)j0 * 256;
                P1 = Pb + (size_t)j1 * 256;
                P2 = Pb + (size_t)j2 * 256;
            }
            #pragma unroll
            for (int j = 0; j < 4; ++j) {
                const int Cc = n0 + wc * 64 + j * 16 + cb;
                float v = acc[i][j][r];
                if (GATHER)
                    v += w0 * bf2f(P0[Cc]) + w1 * bf2f(P1[Cc]) + w2 * bf2f(P2[Cc]);
                if (OUT_BF16)
                    ((u16*)Cout)[(size_t)b * sC + (size_t)R * ldc + Cc] = f2bf(v);
                else
                    ((float*)Cout)[(size_t)b * sC + (size_t)R * ldc + Cc] = v;
                if (STATS == 1) {
                    sj[j] += v;
                    qj[j] += v * v;
                }
                if (STATS == 2) acc[i][j][r] = v;
            }
        }
    }

    if (STATS == 1) {
        #pragma unroll
        for (int j = 0; j < 4; ++j) {
            float s = sj[j], q = qj[j];
            s += __shfl_xor(s, 16); s += __shfl_xor(s, 32);
            q += __shfl_xor(q, 16); q += __shfl_xor(q, 32);
            if (l < 16) {
                sS[wr][wc * 64 + j * 16 + l] = s;
                sQ[wr][wc * 64 + j * 16 + l] = q;
            }
        }
        __syncthreads();
        if (t < 128) {
            const float S = sS[0][t] + sS[1][t];
            const float Q = sQ[0][t] + sQ[1][t];
            const int pblk = blockIdx.z * gridDim.x + blockIdx.x;
            partS[(size_t)pblk * 256 + blockIdx.y * 128 + t] = S;
            partQ[(size_t)pblk * 256 + blockIdx.y * 128 + t] = Q;
        }
    }
    if (STATS == 2) {
        #pragma unroll
        for (int i = 0; i < 4; ++i) {
            #pragma unroll
            for (int r = 0; r < 4; ++r) {
                float s = acc[i][0][r] + acc[i][1][r] + acc[i][2][r] + acc[i][3][r];
                float q = acc[i][0][r] * acc[i][0][r] + acc[i][1][r] * acc[i][1][r] +
                          acc[i][2][r] * acc[i][2][r] + acc[i][3][r] * acc[i][3][r];
                s += __shfl_xor(s, 1); s += __shfl_xor(s, 2);
                s += __shfl_xor(s, 4); s += __shfl_xor(s, 8);
                q += __shfl_xor(q, 1); q += __shfl_xor(q, 2);
                q += __shfl_xor(q, 4); q += __shfl_xor(q, 8);
                if ((l & 15) == 0) {
                    const int row = wr * 64 + i * 16 + (l >> 4) * 4 + r;
                    sS[wc][row] = s;
                    sQ[wc][row] = q;
                }
            }
        }
        __syncthreads();
        if (t < 128) {
            const float S = sS[0][t] + sS[1][t];
            const float Q = sQ[0][t] + sQ[1][t];
            const int pblk = blockIdx.z * gridDim.y + blockIdx.y;
            partS[(size_t)pblk * 128 + t] = S;
            partQ[(size_t)pblk * 128 + t] = Q;
        }
    }
}

// ---------------- BN finalize: reduce partials -> scale/bias ----------------
__global__ __launch_bounds__(1024) void bn_finalize(
    const float* __restrict__ pS, const float* __restrict__ pQ,
    const float* __restrict__ g, const float* __restrict__ beta,
    float* __restrict__ scale, float* __restrict__ bias,
    int C, int np, float cnt)
{
    __shared__ float rs[1024], rq[1024];
    const int t = threadIdx.x;
    const int c = t & (C - 1);
    const int sl = t / C;
    const int nsl = 1024 / C;
    float s = 0.0f, q = 0.0f;
    for (int i = sl; i < np; i += nsl) {
        s += pS[(size_t)i * C + c];
        q += pQ[(size_t)i * C + c];
    }
    rs[t] = s;
    rq[t] = q;
    __syncthreads();
    if (t < C) {
        for (int k = 1; k < nsl; ++k) {
            s += rs[t + k * C];
            q += rq[t + k * C];
        }
        const float mean = s / cnt;
        const float var = q / cnt - mean * mean;
        const float r = rsqrtf(var + 1e-5f);
        const float sc = g[t] * r;
        scale[t] = sc;
        bias[t] = beta[t] - mean * sc;
    }
}

// ---------------- BN2 apply (scale/bias precomputed, broadcast per block) ----------------
__global__ __launch_bounds__(256) void bn2_apply_simple(
    float* __restrict__ Y, const float* __restrict__ scale, const float* __restrict__ bias)
{
    const size_t base = (size_t)blockIdx.x * 1024;
    const int c = (int)((base / Nq) % H2c);
    const float sc = scale[c], bi = bias[c];
    const size_t i = base + threadIdx.x * 4;
    float4 v = *(float4*)&Y[i];
    v.x = fmaxf(0.0f, fmaf(v.x, sc, bi));
    v.y = fmaxf(0.0f, fmaf(v.y, sc, bi));
    v.z = fmaxf(0.0f, fmaf(v.z, sc, bi));
    v.w = fmaxf(0.0f, fmaf(v.w, sc, bi));
    *(float4*)&Y[i] = v;
}

extern "C" void kernel_launch(void* const* d_in, const int* in_sizes, int n_in,
                              void* d_out, int out_size, void* d_ws, size_t ws_size,
                              hipStream_t stream) {
    const float* unknown = (const float*)d_in[0];
    const float* known = (const float*)d_in[1];
    const float* unknow_feats = (const float*)d_in[2];
    const float* known_feats = (const float*)d_in[3];
    const float* W1 = (const float*)d_in[4];
    const float* g1 = (const float*)d_in[5];
    const float* b1 = (const float*)d_in[6];
    const float* W2 = (const float*)d_in[7];
    const float* g2 = (const float*)d_in[8];
    const float* b2 = (const float*)d_in[9];
    float* out = (float*)d_out;

    char* w = (char*)d_ws;
    u16* KFt = (u16*)w; w += (size_t)Bn * Mk * C2c * 2;
    u16* UFt = (u16*)w; w += (size_t)Bn * Nq * C1c * 2;
    u16* W1b = (u16*)w; w += (size_t)H1c * 384 * 2;
    u16* W2b = (u16*)w; w += (size_t)H2c * H1c * 2;
    u16* Ptb = (u16*)w; w += (size_t)Bn * Mk * H1c * 2;
    u16* y1b = (u16*)w; w += (size_t)Bn * Nq * H1c * 2;
    int* idx = (int*)w; w += (size_t)Bn * Nq * 3 * 4;
    float* wgt = (float*)w; w += (size_t)Bn * Nq * 3 * 4;
    float* pS1 = (float*)w; w += (size_t)256 * 256 * 4;
    float* pQ1 = (float*)w; w += (size_t)256 * 256 * 4;
    float* pS2 = (float*)w; w += (size_t)256 * 128 * 4;
    float* pQ2 = (float*)w; w += (size_t)256 * 128 * 4;
    float* scale1 = (float*)w; w += 1024;
    float* bias1 = (float*)w; w += 1024;
    float* scale2 = (float*)w; w += 1024;
    float* bias2 = (float*)w; w += 1024;

    // 1) 3-NN (isolated for attribution)
    knn_kernel<<<1024, 256, 0, stream>>>(unknown, known, idx, wgt);

    // 2) prep: weight cvt + feat transposes
    prep_kernel<<<1664, 256, 0, stream>>>(W1, W2, W1b, W2b,
                                          known_feats, KFt, unknow_feats, UFt);

    // 3) Ptb(b,m,h) = KFt(b,m,:) @ W1[:, :256]^T
    mfma_gemm<0, 1, 0, 0><<<dim3(Mk / 128, H1c / 128, Bn), 256, 0, stream>>>(
        KFt, C2c, (size_t)Mk * C2c,
        W1b, 384, 0,
        Ptb, H1c, (size_t)Mk * H1c,
        C2c / 32, nullptr, nullptr, nullptr, 0,
        nullptr, nullptr, nullptr, nullptr);

    // 4) y1b(b,n,h) = UFt(b,n,:) @ W1[:, 256:]^T + gather(Ptb)  [+ BN1 partial stats]
    mfma_gemm<1, 1, 1, 0><<<dim3(Nq / 128, H1c / 128, Bn), 256, 0, stream>>>(
        UFt, C1c, (size_t)Nq * C1c,
        W1b + C2c, 384, 0,
        y1b, H1c, (size_t)Nq * H1c,
        C1c / 32, Ptb, idx, wgt, Nq,
        nullptr, nullptr, pS1, pQ1);

    // 5) BN1 finalize -> scale1/bias1
    bn_finalize<<<1, 1024, 0, stream>>>(pS1, pQ1, g1, b1, scale1, bias1,
                                        H1c, 256, (float)(Bn * Nq));

    // 6) out(b,o,n) = W2(o,:) @ relu(bn1(y1b(b,n,:)))^T  [+ BN2 partial stats]
    mfma_gemm<0, 0, 2, 1><<<dim3(1, Nq / 128, Bn), 256, 0, stream>>>(
        W2b, H1c, 0,
        y1b, H1c, (size_t)Nq * H1c,
        out, Nq, (size_t)H2c * Nq,
        H1c / 32, nullptr, nullptr, nullptr, 0,
        scale1, bias1, pS2, pQ2);

    // 7) BN2 finalize -> scale2/bias2
    bn_finalize<<<1, 1024, 0, stream>>>(pS2, pQ2, g2, b2, scale2, bias2,
                                        H2c, 256, (float)(Bn * Nq));

    // 8) BN2 apply in place (broadcast scale/bias)
    bn2_apply_simple<<<(Bn * H2c * Nq) / 1024, 256, 0, stream>>>(out, scale2, bias2);
}

// Round 8
// 109.160 us; speedup vs baseline: 1.0740x; 1.0740x over previous
//
#include <hip/hip_runtime.h>
#include <hip/hip_bf16.h>
#include <cstdint>
#include <cstddef>

typedef unsigned short u16;
typedef __attribute__((ext_vector_type(8))) short bf16x8;
typedef __attribute__((ext_vector_type(4))) float f32x4;

constexpr int Bn = 4;
constexpr int Nq = 8192;
constexpr int Mk = 2048;
constexpr int C1c = 128;
constexpr int C2c = 256;
constexpr int H1c = 256;
constexpr int H2c = 128;

__device__ __forceinline__ float bf2f(u16 u) {
    union { uint32_t i; float f; } v;
    v.i = (uint32_t)u << 16;
    return v.f;
}
__device__ __forceinline__ u16 f2bf(float f) {
    const uint32_t x = __float_as_uint(f);
    return (u16)((x + 0x7FFFu + ((x >> 16) & 1u)) >> 16);
}
__device__ __forceinline__ uint32_t cvtpk(float lo, float hi) {
    uint32_t r;
    asm("v_cvt_pk_bf16_f32 %0, %1, %2" : "=v"(r) : "v"(lo), "v"(hi));
    return r;
}

// ================= fused knn + prep =================
// block ranges (knn FIRST — the long pole starts at t=0, prep fills in behind):
// [0,2048) knn (16 lanes/query, 16 q/block)
// [2048,2144) cvt W1 | [2144,2176) cvt W2 | [2176,2688) KF | [2688,3712) UF
__global__ __launch_bounds__(256) void knn_prep_kernel(
    const float* __restrict__ W1, const float* __restrict__ W2,
    u16* __restrict__ W1b, u16* __restrict__ W2b,
    const float* __restrict__ KF, u16* __restrict__ KFt,
    const float* __restrict__ UF, u16* __restrict__ UFt,
    const float* __restrict__ unknown, const float* __restrict__ known,
    int* __restrict__ idx_out, float* __restrict__ w_out)
{
    __shared__ __align__(16) char smem[32768];
    const int bid = blockIdx.x;
    const int t = threadIdx.x;

    if (bid < 2048) {
        // ---- 3-NN: exact f32 compare, 16 lanes/query ----
        float4* kp = (float4*)smem;  // (x, y, z, |k|^2), 32 KB
        const int b = bid >> 9;
        const int n0 = (bid & 511) * 16;

        const float* kb = known + (size_t)b * Mk * 3;
        for (int i = t; i < Mk; i += 256) {
            const float x = kb[i * 3 + 0], y = kb[i * 3 + 1], z = kb[i * 3 + 2];
            kp[i] = make_float4(x, y, z, fmaf(x, x, fmaf(y, y, z * z)));
        }
        __syncthreads();

        const int q = n0 + (t >> 4);
        const int s = t & 15;
        const float* u = unknown + ((size_t)b * Nq + q) * 3;
        const float ux = u[0], uy = u[1], uz = u[2];
        const float nux = -2.0f * ux, nuy = -2.0f * uy, nuz = -2.0f * uz;
        const float uu = fmaf(ux, ux, fmaf(uy, uy, uz * uz));

        // track d' = |k|^2 - 2 u.k  (ordering identical to true squared distance)
        float d0 = 1e30f, d1 = 1e30f, d2 = 1e30f;
        int i0 = 0, i1 = 0, i2 = 0;

        auto ins = [&](float d, int i) {
            const bool c0 = d < d0, c1 = d < d1, c2 = d < d2;
            const float nd0 = fminf(d0, d);
            const float nd1 = __builtin_amdgcn_fmed3f(d0, d, d1);
            const float nd2 = __builtin_amdgcn_fmed3f(d1, d, d2);
            i2 = c1 ? i1 : (c2 ? i : i2);
            i1 = c0 ? i0 : (c1 ? i : i1);
            i0 = c0 ? i : i0;
            d0 = nd0; d1 = nd1; d2 = nd2;
        };

        #pragma unroll 8
        for (int it = 0; it < Mk / 16; ++it) {
            const int m = it * 16 + s;  // 16 consecutive float4 slots: 2-way alias (free)
            const float4 p = kp[m];
            const float d = fmaf(nux, p.x, fmaf(nuy, p.y, fmaf(nuz, p.z, p.w)));
            ins(d, m);
        }
        #pragma unroll
        for (int off = 1; off <= 8; off <<= 1) {
            const float e0 = __shfl_xor(d0, off), e1 = __shfl_xor(d1, off), e2 = __shfl_xor(d2, off);
            const int j0 = __shfl_xor(i0, off), j1 = __shfl_xor(i1, off), j2 = __shfl_xor(i2, off);
            ins(e0, j0);
            ins(e1, j1);
            ins(e2, j2);
        }
        if (s == 0) {
            const float f0 = d0 + uu, f1 = d1 + uu, f2 = d2 + uu;
            const float r0 = 1.0f / (f0 + 1e-8f);
            const float r1 = 1.0f / (f1 + 1e-8f);
            const float r2 = 1.0f / (f2 + 1e-8f);
            const float inv = 1.0f / (r0 + r1 + r2);
            const size_t base = ((size_t)b * Nq + q) * 3;
            idx_out[base + 0] = i0;
            idx_out[base + 1] = i1;
            idx_out[base + 2] = i2;
            w_out[base + 0] = r0 * inv;
            w_out[base + 1] = r1 * inv;
            w_out[base + 2] = r2 * inv;
        }
    } else if (bid < 2176) {
        // ---- flat f32 -> bf16 convert (weights) ----
        const int cb = bid - 2048;
        const float* X = (cb < 96) ? W1 : W2;
        u16* Y = (cb < 96) ? W1b : W2b;
        const int i = ((cb < 96) ? cb : (cb - 96)) * 256 + t;
        const float4 v = *(const float4*)&X[(size_t)i * 4];
        ushort4 o;
        o.x = f2bf(v.x); o.y = f2bf(v.y); o.z = f2bf(v.z); o.w = f2bf(v.w);
        *(ushort4*)&Y[(size_t)i * 4] = o;
    } else {
        // ---- transpose + convert: X (C, M) tile -> Y (M, C) ----
        const float* X;
        u16* Y;
        int C, M, m0, c0;
        if (bid < 2688) {
            const int f = bid - 2176;
            const int b = f >> 7, rem = f & 127;
            C = C2c; M = Mk; m0 = (rem >> 2) * 64; c0 = (rem & 3) * 64;
            X = KF + (size_t)b * C * M;
            Y = KFt + (size_t)b * M * C;
        } else {
            const int f = bid - 2688;
            const int b = f >> 8, rem = f & 255;
            C = C1c; M = Nq; m0 = (rem >> 1) * 64; c0 = (rem & 1) * 64;
            X = UF + (size_t)b * C * M;
            Y = UFt + (size_t)b * M * C;
        }
        float (*T)[65] = (float(*)[65])smem;
        const int m4 = (t & 15) * 4, cr = t >> 4;
        #pragma unroll
        for (int i = 0; i < 4; ++i) {
            const float4 v = *(const float4*)&X[(size_t)(c0 + cr + i * 16) * M + m0 + m4];
            T[cr + i * 16][m4 + 0] = v.x;
            T[cr + i * 16][m4 + 1] = v.y;
            T[cr + i * 16][m4 + 2] = v.z;
            T[cr + i * 16][m4 + 3] = v.w;
        }
        __syncthreads();
        const int c4 = (t & 15) * 4, mr = t >> 4;
        #pragma unroll
        for (int i = 0; i < 4; ++i) {
            const int m = mr + i * 16;
            ushort4 o;
            o.x = f2bf(T[c4 + 0][m]);
            o.y = f2bf(T[c4 + 1][m]);
            o.z = f2bf(T[c4 + 2][m]);
            o.w = f2bf(T[c4 + 3][m]);
            *(ushort4*)&Y[(size_t)(m0 + m) * C + c0 + c4] = o;
        }
    }
}

// ---------------- BN transform for staged B-operand (8 bf16), cvt_pk packed ----------------
__device__ __forceinline__ uint4 bnx(uint4 x, const float* scs, const float* bis, int k) {
    const u16* p = (const u16*)&x;
    const float4 s0 = *(const float4*)&scs[k];
    const float4 s1 = *(const float4*)&scs[k + 4];
    const float4 b0 = *(const float4*)&bis[k];
    const float4 b1 = *(const float4*)&bis[k + 4];
    const float* sa = (const float*)&s0;
    const float* sb = (const float*)&s1;
    const float* ba = (const float*)&b0;
    const float* bb = (const float*)&b1;
    uint4 o;
    uint32_t* po = (uint32_t*)&o;
    #pragma unroll
    for (int w2 = 0; w2 < 2; ++w2) {
        const float a0 = fmaxf(0.0f, fmaf(bf2f(p[2 * w2 + 0]), sa[2 * w2 + 0], ba[2 * w2 + 0]));
        const float a1 = fmaxf(0.0f, fmaf(bf2f(p[2 * w2 + 1]), sa[2 * w2 + 1], ba[2 * w2 + 1]));
        po[w2] = cvtpk(a0, a1);
    }
    #pragma unroll
    for (int w2 = 0; w2 < 2; ++w2) {
        const float a0 = fmaxf(0.0f, fmaf(bf2f(p[4 + 2 * w2 + 0]), sb[2 * w2 + 0], bb[2 * w2 + 0]));
        const float a1 = fmaxf(0.0f, fmaf(bf2f(p[4 + 2 * w2 + 1]), sb[2 * w2 + 1], bb[2 * w2 + 1]));
        po[2 + w2] = cvtpk(a0, a1);
    }
    return o;
}

// ================= bf16 MFMA bt-GEMM: C(M,N) = A(M,K) * Bt(N,K)^T =================
template <int GATHER, int OUT_BF16, int STATS, int BNIN>
__global__ __launch_bounds__(256) void mfma_gemm(
    const u16* __restrict__ A, int lda, size_t sA,
    const u16* __restrict__ Bt, int ldb, size_t sB,
    void* __restrict__ Cout, int ldc, size_t sC,
    int nK,
    const u16* __restrict__ Ptb,
    const int* __restrict__ idx, const float* __restrict__ wgt, int nrows,
    const float* __restrict__ bn_s, const float* __restrict__ bn_b,
    float* __restrict__ partS, float* __restrict__ partQ)
{
    __shared__ u16 As[4096];
    __shared__ u16 Bs[4096];
    __shared__ float scs[256], bis[256];
    __shared__ float sS[2][128], sQ[2][128];

    const int b = blockIdx.z;
    const int m0 = blockIdx.x * 128, n0 = blockIdx.y * 128;
    const int t = threadIdx.x;
    const int l = t & 63, wv = t >> 6;
    const int wr = wv >> 1, wc = wv & 1;

    if (BNIN) {
        scs[t] = bn_s[t];
        bis[t] = bn_b[t];
    }

    const u16* Ab = A + (size_t)b * sA;
    const u16* Btb = Bt + (size_t)b * sB;
    const int rA0 = t >> 2, rA1 = (t + 256) >> 2;
    const int ko = (t & 3) * 8;

    f32x4 acc[4][4];
    const f32x4 z = {0.0f, 0.0f, 0.0f, 0.0f};
    #pragma unroll
    for (int i = 0; i < 4; ++i)
        #pragma unroll
        for (int j = 0; j < 4; ++j) acc[i][j] = z;

    uint4 a0 = *(const uint4*)&Ab[(size_t)(m0 + rA0) * lda + ko];
    uint4 a1 = *(const uint4*)&Ab[(size_t)(m0 + rA1) * lda + ko];
    uint4 b0 = *(const uint4*)&Btb[(size_t)(n0 + rA0) * ldb + ko];
    uint4 b1 = *(const uint4*)&Btb[(size_t)(n0 + rA1) * ldb + ko];
    if (BNIN) __syncthreads();

    for (int kt = 0; kt < nK; ++kt) {
        *(uint4*)&As[t * 8] = a0;
        *(uint4*)&As[(t + 256) * 8] = a1;
        if (BNIN) {
            const int k = kt * 32 + ko;
            *(uint4*)&Bs[t * 8] = bnx(b0, scs, bis, k);
            *(uint4*)&Bs[(t + 256) * 8] = bnx(b1, scs, bis, k);
        } else {
            *(uint4*)&Bs[t * 8] = b0;
            *(uint4*)&Bs[(t + 256) * 8] = b1;
        }
        __syncthreads();
        if (kt + 1 < nK) {
            const int k0 = (kt + 1) * 32;
            a0 = *(const uint4*)&Ab[(size_t)(m0 + rA0) * lda + k0 + ko];
            a1 = *(const uint4*)&Ab[(size_t)(m0 + rA1) * lda + k0 + ko];
            b0 = *(const uint4*)&Btb[(size_t)(n0 + rA0) * ldb + k0 + ko];
            b1 = *(const uint4*)&Btb[(size_t)(n0 + rA1) * ldb + k0 + ko];
        }
        bf16x8 af[4], bf[4];
        #pragma unroll
        for (int f = 0; f < 4; ++f) {
            af[f] = *(const bf16x8*)&As[(wr * 64 + f * 16 + (l & 15)) * 32 + (l >> 4) * 8];
            bf[f] = *(const bf16x8*)&Bs[(wc * 64 + f * 16 + (l & 15)) * 32 + (l >> 4) * 8];
        }
        #pragma unroll
        for (int i = 0; i < 4; ++i)
            #pragma unroll
            for (int j = 0; j < 4; ++j)
                acc[i][j] = __builtin_amdgcn_mfma_f32_16x16x32_bf16(af[i], bf[j], acc[i][j], 0, 0, 0);
        __syncthreads();
    }

    const int cb = l & 15;
    const int rg = (l >> 4) * 4;
    float sj[4] = {0, 0, 0, 0}, qj[4] = {0, 0, 0, 0};
    #pragma unroll
    for (int i = 0; i < 4; ++i) {
        #pragma unroll
        for (int r = 0; r < 4; ++r) {
            const int R = m0 + wr * 64 + i * 16 + rg + r;
            const u16 *P0 = nullptr, *P1 = nullptr, *P2 = nullptr;
            float w0 = 0.0f, w1 = 0.0f, w2 = 0.0f;
            if (GATHER) {
                const size_t ib = ((size_t)b * nrows + R) * 3;
                const int j0 = idx[ib], j1 = idx[ib + 1], j2 = idx[ib + 2];
                w0 = wgt[ib];
                w1 = wgt[ib + 1];
                w2 = wgt[ib + 2];
                const u16* Pb = Ptb + (size_t)b * Mk * 256;
                P0 = Pb + (size_t)j0 * 256;
                P1 = Pb + (size_t)j1 * 256;
                P2 = Pb + (size_t)j2 * 256;
            }
            #pragma unroll
            for (int j = 0; j < 4; ++j) {
                const int Cc = n0 + wc * 64 + j * 16 + cb;
                float v = acc[i][j][r];
                if (GATHER)
                    v += w0 * bf2f(P0[Cc]) + w1 * bf2f(P1[Cc]) + w2 * bf2f(P2[Cc]);
                if (OUT_BF16)
                    ((u16*)Cout)[(size_t)b * sC + (size_t)R * ldc + Cc] = f2bf(v);
                else
                    ((float*)Cout)[(size_t)b * sC + (size_t)R * ldc + Cc] = v;
                if (STATS == 1) {
                    sj[j] += v;
                    qj[j] += v * v;
                }
                if (STATS == 2) acc[i][j][r] = v;
            }
        }
    }

    if (STATS == 1) {
        #pragma unroll
        for (int j = 0; j < 4; ++j) {
            float s = sj[j], q = qj[j];
            s += __shfl_xor(s, 16); s += __shfl_xor(s, 32);
            q += __shfl_xor(q, 16); q += __shfl_xor(q, 32);
            if (l < 16) {
                sS[wr][wc * 64 + j * 16 + l] = s;
                sQ[wr][wc * 64 + j * 16 + l] = q;
            }
        }
        __syncthreads();
        if (t < 128) {
            const float S = sS[0][t] + sS[1][t];
            const float Q = sQ[0][t] + sQ[1][t];
            const int pblk = blockIdx.z * gridDim.x + blockIdx.x;
            partS[(size_t)pblk * 256 + blockIdx.y * 128 + t] = S;
            partQ[(size_t)pblk * 256 + blockIdx.y * 128 + t] = Q;
        }
    }
    if (STATS == 2) {
        #pragma unroll
        for (int i = 0; i < 4; ++i) {
            #pragma unroll
            for (int r = 0; r < 4; ++r) {
                float s = acc[i][0][r] + acc[i][1][r] + acc[i][2][r] + acc[i][3][r];
                float q = acc[i][0][r] * acc[i][0][r] + acc[i][1][r] * acc[i][1][r] +
                          acc[i][2][r] * acc[i][2][r] + acc[i][3][r] * acc[i][3][r];
                s += __shfl_xor(s, 1); s += __shfl_xor(s, 2);
                s += __shfl_xor(s, 4); s += __shfl_xor(s, 8);
                q += __shfl_xor(q, 1); q += __shfl_xor(q, 2);
                q += __shfl_xor(q, 4); q += __shfl_xor(q, 8);
                if ((l & 15) == 0) {
                    const int row = wr * 64 + i * 16 + (l >> 4) * 4 + r;
                    sS[wc][row] = s;
                    sQ[wc][row] = q;
                }
            }
        }
        __syncthreads();
        if (t < 128) {
            const float S = sS[0][t] + sS[1][t];
            const float Q = sQ[0][t] + sQ[1][t];
            const int pblk = blockIdx.z * gridDim.y + blockIdx.y;
            partS[(size_t)pblk * 128 + t] = S;
            partQ[(size_t)pblk * 128 + t] = Q;
        }
    }
}

// ---------------- BN1 finalize: reduce partials -> scale/bias ----------------
__global__ __launch_bounds__(1024) void bn_finalize(
    const float* __restrict__ pS, const float* __restrict__ pQ,
    const float* __restrict__ g, const float* __restrict__ beta,
    float* __restrict__ scale, float* __restrict__ bias,
    int C, int np, float cnt)
{
    __shared__ float rs[1024], rq[1024];
    const int t = threadIdx.x;
    const int c = t & (C - 1);
    const int sl = t / C;
    const int nsl = 1024 / C;
    float s = 0.0f, q = 0.0f;
    for (int i = sl; i < np; i += nsl) {
        s += pS[(size_t)i * C + c];
        q += pQ[(size_t)i * C + c];
    }
    rs[t] = s;
    rq[t] = q;
    __syncthreads();
    if (t < C) {
        for (int k = 1; k < nsl; ++k) {
            s += rs[t + k * C];
            q += rq[t + k * C];
        }
        const float mean = s / cnt;
        const float var = q / cnt - mean * mean;
        const float r = rsqrtf(var + 1e-5f);
        const float sc = g[t] * r;
        scale[t] = sc;
        bias[t] = beta[t] - mean * sc;
    }
}

// ---------------- fused BN2 finalize + apply ----------------
__global__ __launch_bounds__(256) void bn2_apply_kernel(
    float* __restrict__ Y,
    const float* __restrict__ pS, const float* __restrict__ pQ,
    const float* __restrict__ g, const float* __restrict__ beta)
{
    __shared__ float rs[256], rq[256];
    const int t = threadIdx.x;
    const size_t base = (size_t)blockIdx.x * 1024;
    const int c = (int)((base / Nq) % H2c);

    rs[t] = pS[(size_t)t * 128 + c];
    rq[t] = pQ[(size_t)t * 128 + c];
    __syncthreads();
    for (int off = 128; off > 0; off >>= 1) {
        if (t < off) {
            rs[t] += rs[t + off];
            rq[t] += rq[t + off];
        }
        __syncthreads();
    }
    if (t == 0) {
        const float cnt = (float)(Bn * Nq);
        const float mean = rs[0] / cnt;
        const float var = rq[0] / cnt - mean * mean;
        const float r = rsqrtf(var + 1e-5f);
        const float sc = g[c] * r;
        rs[0] = sc;
        rq[0] = beta[c] - mean * sc;
    }
    __syncthreads();
    const float sc = rs[0], bi = rq[0];
    float4 v = *(float4*)&Y[base + t * 4];
    v.x = fmaxf(0.0f, fmaf(v.x, sc, bi));
    v.y = fmaxf(0.0f, fmaf(v.y, sc, bi));
    v.z = fmaxf(0.0f, fmaf(v.z, sc, bi));
    v.w = fmaxf(0.0f, fmaf(v.w, sc, bi));
    *(float4*)&Y[base + t * 4] = v;
}

extern "C" void kernel_launch(void* const* d_in, const int* in_sizes, int n_in,
                              void* d_out, int out_size, void* d_ws, size_t ws_size,
                              hipStream_t stream) {
    const float* unknown = (const float*)d_in[0];
    const float* known = (const float*)d_in[1];
    const float* unknow_feats = (const float*)d_in[2];
    const float* known_feats = (const float*)d_in[3];
    const float* W1 = (const float*)d_in[4];
    const float* g1 = (const float*)d_in[5];
    const float* b1 = (const float*)d_in[6];
    const float* W2 = (const float*)d_in[7];
    const float* g2 = (const float*)d_in[8];
    const float* b2 = (const float*)d_in[9];
    float* out = (float*)d_out;

    char* w = (char*)d_ws;
    u16* KFt = (u16*)w; w += (size_t)Bn * Mk * C2c * 2;
    u16* UFt = (u16*)w; w += (size_t)Bn * Nq * C1c * 2;
    u16* W1b = (u16*)w; w += (size_t)H1c * 384 * 2;
    u16* W2b = (u16*)w; w += (size_t)H2c * H1c * 2;
    u16* Ptb = (u16*)w; w += (size_t)Bn * Mk * H1c * 2;
    u16* y1b = (u16*)w; w += (size_t)Bn * Nq * H1c * 2;
    int* idx = (int*)w; w += (size_t)Bn * Nq * 3 * 4;
    float* wgt = (float*)w; w += (size_t)Bn * Nq * 3 * 4;
    float* pS1 = (float*)w; w += (size_t)256 * 256 * 4;
    float* pQ1 = (float*)w; w += (size_t)256 * 256 * 4;
    float* pS2 = (float*)w; w += (size_t)256 * 128 * 4;
    float* pQ2 = (float*)w; w += (size_t)256 * 128 * 4;
    float* scale1 = (float*)w; w += 1024;
    float* bias1 = (float*)w; w += 1024;

    // 1) fused knn (first, 2048 blocks) + prep (weight cvt + feat transposes)
    knn_prep_kernel<<<3712, 256, 0, stream>>>(W1, W2, W1b, W2b,
                                              known_feats, KFt, unknow_feats, UFt,
                                              unknown, known, idx, wgt);

    // 2) Ptb(b,m,h) = KFt(b,m,:) @ W1[:, :256]^T
    mfma_gemm<0, 1, 0, 0><<<dim3(Mk / 128, H1c / 128, Bn), 256, 0, stream>>>(
        KFt, C2c, (size_t)Mk * C2c,
        W1b, 384, 0,
        Ptb, H1c, (size_t)Mk * H1c,
        C2c / 32, nullptr, nullptr, nullptr, 0,
        nullptr, nullptr, nullptr, nullptr);

    // 3) y1b(b,n,h) = UFt(b,n,:) @ W1[:, 256:]^T + gather(Ptb)  [+ BN1 partial stats]
    mfma_gemm<1, 1, 1, 0><<<dim3(Nq / 128, H1c / 128, Bn), 256, 0, stream>>>(
        UFt, C1c, (size_t)Nq * C1c,
        W1b + C2c, 384, 0,
        y1b, H1c, (size_t)Nq * H1c,
        C1c / 32, Ptb, idx, wgt, Nq,
        nullptr, nullptr, pS1, pQ1);

    // 4) BN1 finalize -> scale1/bias1
    bn_finalize<<<1, 1024, 0, stream>>>(pS1, pQ1, g1, b1, scale1, bias1,
                                        H1c, 256, (float)(Bn * Nq));

    // 5) out(b,o,n) = W2(o,:) @ relu(bn1(y1b(b,n,:)))^T  [+ BN2 partial stats]
    mfma_gemm<0, 0, 2, 1><<<dim3(1, Nq / 128, Bn), 256, 0, stream>>>(
        W2b, H1c, 0,
        y1b, H1c, (size_t)Nq * H1c,
        out, Nq, (size_t)H2c * Nq,
        H1c / 32, nullptr, nullptr, nullptr, 0,
        scale1, bias1, pS2, pQ2);

    // 6) BN2 finalize (per-block) + apply in place
    bn2_apply_kernel<<<(Bn * H2c * Nq) / 1024, 256, 0, stream>>>(out, pS2, pQ2, g2, b2);
}